// Round 1
// baseline (1414.941 us; speedup 1.0000x reference)
//
#include <hip/hip_runtime.h>
#include <math.h>

#define AST 68      // sActT row stride in floats (64 atoms + 4 pad; 272B, 16B-aligned)
#define WST 132     // sWT row stride in floats (528B, 16B-aligned)

__device__ __forceinline__ float ssp_f(float x) {
  // softplus(x) - log(2), numerically stable
  return fmaxf(x, 0.f) + log1pf(expf(-fabsf(x))) - 0.6931471805599453f;
}

__device__ __forceinline__ unsigned enc_max(float f) {
  unsigned u = __float_as_uint(f);
  return (u & 0x80000000u) ? ~u : (u | 0x80000000u);
}
__device__ __forceinline__ float dec_max(unsigned u) {
  return (u & 0x80000000u) ? __uint_as_float(u & 0x7fffffffu) : __uint_as_float(~u);
}

// ---------------------------------------------------------------------------
// K1: per-run prep. A_c[g] = sum_f Wk[f,c]*Wq[f,g]; b_c = sum_f Wk[f,c]*bq[f];
// zero molsum, init Mu/Z.
__global__ void k_prep(const float* __restrict__ Wq, const float* __restrict__ bq,
                       const float* __restrict__ Wk,
                       float* __restrict__ A, float* __restrict__ bv,
                       unsigned* __restrict__ Mu, float* __restrict__ Z,
                       float* __restrict__ molsum, int B) {
  int t = threadIdx.x;
  if (blockIdx.x == 0) {
    if (t < 128) {
      float a0 = 0.f, a1 = 0.f;
      for (int f = 0; f < 128; ++f) {
        float wq = Wq[f * 128 + t];
        a0 += Wk[f * 2 + 0] * wq;
        a1 += Wk[f * 2 + 1] * wq;
      }
      A[t] = a0; A[128 + t] = a1;
    }
    if (t == 0) {
      float b0 = 0.f, b1 = 0.f;
      for (int f = 0; f < 128; ++f) {
        b0 += Wk[f * 2 + 0] * bq[f];
        b1 += Wk[f * 2 + 1] * bq[f];
      }
      bv[0] = b0; bv[1] = b1;
      *Mu = 0u;        // encodes -inf under enc_max ordering
      *Z = 0.f;
    }
  }
  int m = blockIdx.x * 256 + t;
  if (m < B) molsum[m] = 0.f;
}

// ---------------------------------------------------------------------------
// K1t: transpose W1,W2,Wo (128x128 each) into WT[mtx][g*128+f] = W[f*128+g]
__global__ void k_transpose(const float* __restrict__ W1, const float* __restrict__ W2,
                            const float* __restrict__ Wo, float* __restrict__ WT) {
  int gid = blockIdx.x * 256 + threadIdx.x;   // 0..49151
  int mtx = gid >> 14;
  int r = gid & 16383;
  int g = r >> 7, f = r & 127;
  const float* W = (mtx == 0) ? W1 : ((mtx == 1) ? W2 : Wo);
  WT[gid] = W[f * 128 + g];
}

// ---------------------------------------------------------------------------
// K2: w_i = (kf0*(emb_i.A0 + b0) + kf1*(emb_i.A1 + b1)) / sqrt(128); global max.
// 16 threads per atom, 16 atoms per block.
__global__ __launch_bounds__(256) void k_w(
    const float* __restrict__ emb, const float* __restrict__ ef,
    const int* __restrict__ idx, const float* __restrict__ A,
    const float* __restrict__ bv, float* __restrict__ wvec,
    unsigned* __restrict__ Mu, int N) {
  __shared__ float sA[256];
  __shared__ float sred[4];
  int t = threadIdx.x;
  sA[t] = A[t];
  __syncthreads();

  int atom = blockIdx.x * 16 + (t >> 4);
  int sub = t & 15;
  float p0 = 0.f, p1 = 0.f;
  if (atom < N) {
    const float4* row = (const float4*)(emb + (size_t)atom * 128);
    float4 x0 = row[sub * 2];
    float4 x1 = row[sub * 2 + 1];
    int gb = sub * 8;
    p0 = x0.x * sA[gb + 0] + x0.y * sA[gb + 1] + x0.z * sA[gb + 2] + x0.w * sA[gb + 3]
       + x1.x * sA[gb + 4] + x1.y * sA[gb + 5] + x1.z * sA[gb + 6] + x1.w * sA[gb + 7];
    p1 = x0.x * sA[128 + gb + 0] + x0.y * sA[128 + gb + 1] + x0.z * sA[128 + gb + 2] + x0.w * sA[128 + gb + 3]
       + x1.x * sA[128 + gb + 4] + x1.y * sA[128 + gb + 5] + x1.z * sA[128 + gb + 6] + x1.w * sA[128 + gb + 7];
  }
  #pragma unroll
  for (int off = 8; off >= 1; off >>= 1) {
    p0 += __shfl_down(p0, off, 16);
    p1 += __shfl_down(p1, off, 16);
  }
  float myw = -3.4e38f;
  if (sub == 0 && atom < N) {
    int m = idx[atom];
    float e = ef[m];
    float e0 = fmaxf(e, 0.f), e1 = fmaxf(-e, 0.f);
    float kf0 = fminf(e0, 1.f), kf1 = fminf(e1, 1.f);
    float b0 = bv[0], b1 = bv[1];
    float wv = (kf0 * (p0 + b0) + kf1 * (p1 + b1)) * 0.08838834764831845f; // 1/sqrt(128)
    wvec[atom] = wv;
    myw = wv;
  }
  #pragma unroll
  for (int off = 32; off >= 1; off >>= 1)
    myw = fmaxf(myw, __shfl_down(myw, off));
  if ((t & 63) == 0) sred[t >> 6] = myw;
  __syncthreads();
  if (t == 0) {
    float bm = fmaxf(fmaxf(sred[0], sred[1]), fmaxf(sred[2], sred[3]));
    atomicMax(Mu, enc_max(bm));
  }
}

// ---------------------------------------------------------------------------
// K3: E = exp(w - M); molsum[m] += E (wave-segmented-scan to cut atomics); Z += E.
__global__ __launch_bounds__(256) void k_expsum(
    const float* __restrict__ wvec, const int* __restrict__ idx,
    const unsigned* __restrict__ Mu, float* __restrict__ molsum,
    float* __restrict__ Z, int N) {
  __shared__ float sred[4];
  int t = threadIdx.x;
  int i = blockIdx.x * 256 + t;
  float M = dec_max(*Mu);
  float E = 0.f;
  int m = -1;
  if (i < N) {
    m = idx[i];
    E = expf(wvec[i] - M);
  }
  // segmented inclusive scan over contiguous equal-m runs within the wave
  float v = E;
  int lane = t & 63;
  #pragma unroll
  for (int off = 1; off < 64; off <<= 1) {
    float vv = __shfl_up(v, off);
    int mm = __shfl_up(m, off);
    if (lane >= off && mm == m) v += vv;
  }
  int mnext = __shfl_down(m, 1);
  bool tail = (lane == 63) || (mnext != m);
  if (tail && m >= 0) atomicAdd(&molsum[m], v);
  // Z: full wave sum then block sum
  float s = E;
  #pragma unroll
  for (int off = 32; off >= 1; off >>= 1) s += __shfl_down(s, off);
  if (lane == 0) sred[t >> 6] = s;
  __syncthreads();
  if (t == 0) atomicAdd(Z, sred[0] + sred[1] + sred[2] + sred[3]);
}

// ---------------------------------------------------------------------------
// K4: per-atom scale -> x = scale*v_m (rank-1 from c0,c1) -> 3 fused GEMMs.
// 64 atoms/block, 256 threads, 4 atoms x 8 f register tile.
// Activations in LDS transposed [g][atom] (one b128 per 4 atoms).
// Weights (pre-transposed [g][f]) staged in 64-row LDS chunks.
__global__ __launch_bounds__(256, 2) void k_mlp(
    const float* __restrict__ wvec, const int* __restrict__ idx,
    const float* __restrict__ ef, const float* __restrict__ Wv,
    const float* __restrict__ WT, const float* __restrict__ molsum,
    const unsigned* __restrict__ Mu, const float* __restrict__ Zp,
    float* __restrict__ out, int N) {
  __shared__ float sWT[64 * WST];      // 33.8 KB
  __shared__ float sActT[128 * AST];   // 34.8 KB
  __shared__ float sC0[64], sC1[64];
  __shared__ float sWv0[128], sWv1[128];

  int t = threadIdx.x;
  int base = blockIdx.x * 64;

  if (t < 64) {
    int i = base + t;
    float c0 = 0.f, c1 = 0.f;
    if (i < N) {
      float M = dec_max(*Mu);
      float Zv = *Zp;
      int m = idx[i];
      float E = expf(wvec[i] - M);
      float sc = E / (molsum[m] + 1e-8f * Zv);
      float e = ef[m];
      c0 = sc * fmaxf(e, 0.f);
      c1 = sc * fmaxf(-e, 0.f);
    }
    sC0[t] = c0; sC1[t] = c1;
  }
  if (t < 128) {
    sWv0[t] = Wv[t * 2 + 0];
    sWv1[t] = Wv[t * 2 + 1];
  }
  __syncthreads();

  int ao = (t & 15) * 4;        // atom group (fast across lanes -> b128 reads)
  int fo = (t >> 4) * 8;        // f group

  float c0a[4], c1a[4];
  #pragma unroll
  for (int j = 0; j < 4; ++j) { c0a[j] = sC0[ao + j]; c1a[j] = sC1[ao + j]; }

  // initial activations: sActT[f][a] = ssp(c0*Wv0[f] + c1*Wv1[f])
  #pragma unroll
  for (int k = 0; k < 8; ++k) {
    int f = fo + k;
    float w0 = sWv0[f], w1 = sWv1[f];
    float4 v;
    v.x = ssp_f(c0a[0] * w0 + c1a[0] * w1);
    v.y = ssp_f(c0a[1] * w0 + c1a[1] * w1);
    v.z = ssp_f(c0a[2] * w0 + c1a[2] * w1);
    v.w = ssp_f(c0a[3] * w0 + c1a[3] * w1);
    *(float4*)(sActT + f * AST + ao) = v;
  }

  int lf4 = (t & 31) * 4;   // weight staging: column
  int lg0 = t >> 5;         // weight staging: row base (+8k)

  for (int layer = 0; layer < 3; ++layer) {
    const float* Wl = WT + layer * 16384;
    float acc[4][8];
    #pragma unroll
    for (int j = 0; j < 4; ++j)
      #pragma unroll
      for (int k = 0; k < 8; ++k) acc[j][k] = 0.f;

    for (int h = 0; h < 2; ++h) {
      __syncthreads();   // prior sWT reads + sActT writes complete
      #pragma unroll
      for (int k = 0; k < 8; ++k) {
        int g = lg0 + 8 * k;
        *(float4*)(sWT + g * WST + lf4) =
            *(const float4*)(Wl + (size_t)(h * 64 + g) * 128 + lf4);
      }
      __syncthreads();   // sWT chunk ready
      const float* actBase = sActT + (h * 64) * AST + ao;
      #pragma unroll 8
      for (int g = 0; g < 64; ++g) {
        float4 sv = *(const float4*)(actBase + (size_t)g * AST);
        float4 w0 = *(const float4*)(sWT + g * WST + fo);
        float4 w1 = *(const float4*)(sWT + g * WST + fo + 4);
        float sj[4] = {sv.x, sv.y, sv.z, sv.w};
        #pragma unroll
        for (int j = 0; j < 4; ++j) {
          acc[j][0] += sj[j] * w0.x; acc[j][1] += sj[j] * w0.y;
          acc[j][2] += sj[j] * w0.z; acc[j][3] += sj[j] * w0.w;
          acc[j][4] += sj[j] * w1.x; acc[j][5] += sj[j] * w1.y;
          acc[j][6] += sj[j] * w1.z; acc[j][7] += sj[j] * w1.w;
        }
      }
    }
    __syncthreads();     // all sActT reads of this layer complete

    if (layer == 2) {
      // out = acc
      #pragma unroll
      for (int j = 0; j < 4; ++j) {
        int i = base + ao + j;
        if (i < N) {
          float4 o0 = {acc[j][0], acc[j][1], acc[j][2], acc[j][3]};
          float4 o1 = {acc[j][4], acc[j][5], acc[j][6], acc[j][7]};
          *(float4*)(out + (size_t)i * 128 + fo) = o0;
          *(float4*)(out + (size_t)i * 128 + fo + 4) = o1;
        }
      }
    } else if (layer == 0) {
      // s2 = ssp(h1)
      #pragma unroll
      for (int k = 0; k < 8; ++k) {
        int f = fo + k;
        float4 v;
        v.x = ssp_f(acc[0][k]);
        v.y = ssp_f(acc[1][k]);
        v.z = ssp_f(acc[2][k]);
        v.w = ssp_f(acc[3][k]);
        *(float4*)(sActT + f * AST + ao) = v;
      }
    } else {
      // s3 = ssp(x + t2), x recomputed from c0,c1
      #pragma unroll
      for (int k = 0; k < 8; ++k) {
        int f = fo + k;
        float w0 = sWv0[f], w1 = sWv1[f];
        float4 v;
        v.x = ssp_f(c0a[0] * w0 + c1a[0] * w1 + acc[0][k]);
        v.y = ssp_f(c0a[1] * w0 + c1a[1] * w1 + acc[1][k]);
        v.z = ssp_f(c0a[2] * w0 + c1a[2] * w1 + acc[2][k]);
        v.w = ssp_f(c0a[3] * w0 + c1a[3] * w1 + acc[3][k]);
        *(float4*)(sActT + f * AST + ao) = v;
      }
    }
  }
}

// ---------------------------------------------------------------------------
extern "C" void kernel_launch(void* const* d_in, const int* in_sizes, int n_in,
                              void* d_out, int out_size, void* d_ws, size_t ws_size,
                              hipStream_t stream) {
  const float* emb = (const float*)d_in[0];
  const float* ef  = (const float*)d_in[1];
  const int*   idx = (const int*)d_in[2];
  const float* Wq  = (const float*)d_in[3];
  const float* bq  = (const float*)d_in[4];
  const float* Wk  = (const float*)d_in[5];
  const float* Wv  = (const float*)d_in[6];
  const float* W1  = (const float*)d_in[7];
  const float* W2  = (const float*)d_in[8];
  const float* Wo  = (const float*)d_in[9];
  float* out = (float*)d_out;

  int N = in_sizes[0] / 128;
  int B = in_sizes[1];

  float* ws = (float*)d_ws;
  float* A      = ws;                      // 256
  float* bv     = ws + 256;                // 2
  unsigned* Mu  = (unsigned*)(ws + 258);   // 1
  float* Z      = ws + 259;                // 1
  float* molsum = ws + 260;                // B
  float* wvec   = ws + 260 + B;            // N
  size_t offWT  = ((size_t)260 + B + N + 3) & ~(size_t)3;  // 16B-align
  float* WT     = ws + offWT;              // 3*16384

  k_prep<<<(B + 255) / 256, 256, 0, stream>>>(Wq, bq, Wk, A, bv, Mu, Z, molsum, B);
  k_transpose<<<192, 256, 0, stream>>>(W1, W2, Wo, WT);
  k_w<<<(N + 15) / 16, 256, 0, stream>>>(emb, ef, idx, A, bv, wvec, Mu, N);
  k_expsum<<<(N + 255) / 256, 256, 0, stream>>>(wvec, idx, Mu, molsum, Z, N);
  k_mlp<<<(N + 63) / 64, 256, 0, stream>>>(wvec, idx, ef, Wv, WT, molsum, Mu, Z, out, N);
}

// Round 2
// 1175.844 us; speedup vs baseline: 1.2033x; 1.2033x over previous
//
#include <hip/hip_runtime.h>
#include <math.h>

typedef __attribute__((ext_vector_type(8))) short bf16x8;
typedef __attribute__((ext_vector_type(4))) float f32x4;

#define ACT_ST 136   // act row stride in shorts (128 + 8 pad; 272 B)

__device__ __forceinline__ float ssp_f(float x) {
  // softplus(x) - log(2), numerically stable
  return fmaxf(x, 0.f) + log1pf(expf(-fabsf(x))) - 0.6931471805599453f;
}

__device__ __forceinline__ unsigned enc_max(float f) {
  unsigned u = __float_as_uint(f);
  return (u & 0x80000000u) ? ~u : (u | 0x80000000u);
}
__device__ __forceinline__ float dec_max(unsigned u) {
  return (u & 0x80000000u) ? __uint_as_float(u & 0x7fffffffu) : __uint_as_float(~u);
}

// round-to-nearest-even f32 -> bf16 bits (finite inputs)
__device__ __forceinline__ unsigned short f2bf(float x) {
  unsigned u = __float_as_uint(x);
  return (unsigned short)((u + 0x7fffu + ((u >> 16) & 1u)) >> 16);
}
__device__ __forceinline__ float bf2f(unsigned short b) {
  return __uint_as_float(((unsigned)b) << 16);
}

// split 4 floats to hi/lo bf16 and store as 8B each
__device__ __forceinline__ void split_store4(short* ph, short* pl, const float* s) {
  unsigned short h[4], l[4];
#pragma unroll
  for (int r = 0; r < 4; ++r) {
    h[r] = f2bf(s[r]);
    l[r] = f2bf(s[r] - bf2f(h[r]));
  }
  uint2 hv, lv;
  hv.x = (unsigned)h[0] | ((unsigned)h[1] << 16);
  hv.y = (unsigned)h[2] | ((unsigned)h[3] << 16);
  lv.x = (unsigned)l[0] | ((unsigned)l[1] << 16);
  lv.y = (unsigned)l[2] | ((unsigned)l[3] << 16);
  *(uint2*)ph = hv;
  *(uint2*)pl = lv;
}

// ---------------------------------------------------------------------------
// K1: per-run prep. A_c[g] = sum_f Wk[f,c]*Wq[f,g]; b_c = sum_f Wk[f,c]*bq[f];
// zero molsum, init Mu/Z.
__global__ void k_prep(const float* __restrict__ Wq, const float* __restrict__ bq,
                       const float* __restrict__ Wk,
                       float* __restrict__ A, float* __restrict__ bv,
                       unsigned* __restrict__ Mu, float* __restrict__ Z,
                       float* __restrict__ molsum, int B) {
  int t = threadIdx.x;
  if (blockIdx.x == 0) {
    if (t < 128) {
      float a0 = 0.f, a1 = 0.f;
      for (int f = 0; f < 128; ++f) {
        float wq = Wq[f * 128 + t];
        a0 += Wk[f * 2 + 0] * wq;
        a1 += Wk[f * 2 + 1] * wq;
      }
      A[t] = a0; A[128 + t] = a1;
    }
    if (t == 0) {
      float b0 = 0.f, b1 = 0.f;
      for (int f = 0; f < 128; ++f) {
        b0 += Wk[f * 2 + 0] * bq[f];
        b1 += Wk[f * 2 + 1] * bq[f];
      }
      bv[0] = b0; bv[1] = b1;
      *Mu = 0u;        // encodes -inf under enc_max ordering
      *Z = 0.f;
    }
  }
  int m = blockIdx.x * 256 + t;
  if (m < B) molsum[m] = 0.f;
}

// ---------------------------------------------------------------------------
// K1b: split W1,W2,Wo (row-major [f][g], no transpose) into bf16 hi/lo parts.
__global__ void k_split(const float* __restrict__ W1, const float* __restrict__ W2,
                        const float* __restrict__ Wo,
                        short* __restrict__ WH, short* __restrict__ WL) {
  int gid = blockIdx.x * 256 + threadIdx.x;   // 0..49151
  const float* W = (gid < 16384) ? W1 : ((gid < 32768) ? W2 : Wo);
  float v = W[gid & 16383];
  unsigned short h = f2bf(v);
  WH[gid] = (short)h;
  WL[gid] = (short)f2bf(v - bf2f(h));
}

// ---------------------------------------------------------------------------
// K2: w_i = (kf0*(emb_i.A0 + b0) + kf1*(emb_i.A1 + b1)) / sqrt(128); global max.
__global__ __launch_bounds__(256) void k_w(
    const float* __restrict__ emb, const float* __restrict__ ef,
    const int* __restrict__ idx, const float* __restrict__ A,
    const float* __restrict__ bv, float* __restrict__ wvec,
    unsigned* __restrict__ Mu, int N) {
  __shared__ float sA[256];
  __shared__ float sred[4];
  int t = threadIdx.x;
  sA[t] = A[t];
  __syncthreads();

  int atom = blockIdx.x * 16 + (t >> 4);
  int sub = t & 15;
  float p0 = 0.f, p1 = 0.f;
  if (atom < N) {
    const float4* row = (const float4*)(emb + (size_t)atom * 128);
    float4 x0 = row[sub * 2];
    float4 x1 = row[sub * 2 + 1];
    int gb = sub * 8;
    p0 = x0.x * sA[gb + 0] + x0.y * sA[gb + 1] + x0.z * sA[gb + 2] + x0.w * sA[gb + 3]
       + x1.x * sA[gb + 4] + x1.y * sA[gb + 5] + x1.z * sA[gb + 6] + x1.w * sA[gb + 7];
    p1 = x0.x * sA[128 + gb + 0] + x0.y * sA[128 + gb + 1] + x0.z * sA[128 + gb + 2] + x0.w * sA[128 + gb + 3]
       + x1.x * sA[128 + gb + 4] + x1.y * sA[128 + gb + 5] + x1.z * sA[128 + gb + 6] + x1.w * sA[128 + gb + 7];
  }
#pragma unroll
  for (int off = 8; off >= 1; off >>= 1) {
    p0 += __shfl_down(p0, off, 16);
    p1 += __shfl_down(p1, off, 16);
  }
  float myw = -3.4e38f;
  if (sub == 0 && atom < N) {
    int m = idx[atom];
    float e = ef[m];
    float kf0 = fminf(fmaxf(e, 0.f), 1.f);
    float kf1 = fminf(fmaxf(-e, 0.f), 1.f);
    float wv = (kf0 * (p0 + bv[0]) + kf1 * (p1 + bv[1])) * 0.08838834764831845f;
    wvec[atom] = wv;
    myw = wv;
  }
#pragma unroll
  for (int off = 32; off >= 1; off >>= 1)
    myw = fmaxf(myw, __shfl_down(myw, off));
  if ((t & 63) == 0) sred[t >> 6] = myw;
  __syncthreads();
  if (t == 0) {
    float bm = fmaxf(fmaxf(sred[0], sred[1]), fmaxf(sred[2], sred[3]));
    atomicMax(Mu, enc_max(bm));
  }
}

// ---------------------------------------------------------------------------
// K3: E = exp(w - M); molsum[m] += E (segmented scan); Z += E.
__global__ __launch_bounds__(256) void k_expsum(
    const float* __restrict__ wvec, const int* __restrict__ idx,
    const unsigned* __restrict__ Mu, float* __restrict__ molsum,
    float* __restrict__ Z, int N) {
  __shared__ float sred[4];
  int t = threadIdx.x;
  int i = blockIdx.x * 256 + t;
  float M = dec_max(*Mu);
  float E = 0.f;
  int m = -1;
  if (i < N) {
    m = idx[i];
    E = expf(wvec[i] - M);
  }
  float v = E;
  int lane = t & 63;
#pragma unroll
  for (int off = 1; off < 64; off <<= 1) {
    float vv = __shfl_up(v, off);
    int mm = __shfl_up(m, off);
    if (lane >= off && mm == m) v += vv;
  }
  int mnext = __shfl_down(m, 1);
  bool tail = (lane == 63) || (mnext != m);
  if (tail && m >= 0) atomicAdd(&molsum[m], v);
  float s = E;
#pragma unroll
  for (int off = 32; off >= 1; off >>= 1) s += __shfl_down(s, off);
  if (lane == 0) sred[t >> 6] = s;
  __syncthreads();
  if (t == 0) atomicAdd(Z, sred[0] + sred[1] + sred[2] + sred[3]);
}

// ---------------------------------------------------------------------------
// K4: MFMA bf16x3 fused 3-layer MLP.
// C[f][atom] = sum_g W[f][g]*act[atom][g]:
//   A-operand = W rows (global, row-major, hi/lo bf16)  A[m=f][k=g]
//   B-operand = act from LDS [atom][g]                  B[k=g][n=atom]
//   D: col(lane&15)=atom, rows(4*quad+reg)=4 consecutive f -> b64 writeback.
// Block: 64 atoms x 128 f, 4 waves (wave w owns f in [32w,32w+32)).
__global__ __launch_bounds__(256, 2) void k_mlp(
    const float* __restrict__ wvec, const int* __restrict__ idx,
    const float* __restrict__ ef, const float* __restrict__ Wv,
    const short* __restrict__ WH, const short* __restrict__ WL,
    const float* __restrict__ molsum, const unsigned* __restrict__ Mu,
    const float* __restrict__ Zp, float* __restrict__ out, int N) {
  __shared__ short actH[2][64 * ACT_ST];   // 17408 B each
  __shared__ short actL[2][64 * ACT_ST];
  __shared__ float sC0[64], sC1[64], sWv0[128], sWv1[128];

  int t = threadIdx.x;
  int base = blockIdx.x * 64;

  if (t < 64) {
    int i = base + t;
    float c0 = 0.f, c1 = 0.f;
    if (i < N) {
      float M = dec_max(*Mu);
      float Zv = *Zp;
      int m = idx[i];
      float E = expf(wvec[i] - M);
      float sc = E / (molsum[m] + 1e-8f * Zv);
      float e = ef[m];
      c0 = sc * fmaxf(e, 0.f);
      c1 = sc * fmaxf(-e, 0.f);
    }
    sC0[t] = c0; sC1[t] = c1;
  }
  if (t < 128) {
    sWv0[t] = Wv[t * 2 + 0];
    sWv1[t] = Wv[t * 2 + 1];
  }
  __syncthreads();

  // initial activations: act0[atom][g] = ssp(c0*Wv0[g] + c1*Wv1[g]), hi/lo bf16
  {
    int a = t & 63;
    int gb = (t >> 6) * 32;
    float c0 = sC0[a], c1 = sC1[a];
#pragma unroll
    for (int g = 0; g < 32; g += 4) {
      float s[4];
#pragma unroll
      for (int r = 0; r < 4; ++r)
        s[r] = ssp_f(c0 * sWv0[gb + g + r] + c1 * sWv1[gb + g + r]);
      split_store4(&actH[0][a * ACT_ST + gb + g], &actL[0][a * ACT_ST + gb + g], s);
    }
  }
  __syncthreads();

  int lane = t & 15;
  int quad = (t >> 4) & 3;
  int wv_ = __builtin_amdgcn_readfirstlane(t >> 6);   // wave id 0..3

  int cur = 0;
  for (int layer = 0; layer < 3; ++layer) {
    const short* Wh = WH + layer * 16384;
    const short* Wl = WL + layer * 16384;

    // preload all A-fragments (weights) for this wave's 32 f rows
    bf16x8 Ah[2][4], Al[2][4];
#pragma unroll
    for (int m = 0; m < 2; ++m) {
      int f = 32 * wv_ + 16 * m + lane;
#pragma unroll
      for (int k = 0; k < 4; ++k) {
        int off = f * 128 + 32 * k + 8 * quad;
        Ah[m][k] = *(const bf16x8*)(Wh + off);
        Al[m][k] = *(const bf16x8*)(Wl + off);
      }
    }

    f32x4 acc[2][4];
#pragma unroll
    for (int m = 0; m < 2; ++m)
#pragma unroll
      for (int n = 0; n < 4; ++n)
        acc[m][n] = (f32x4){0.f, 0.f, 0.f, 0.f};

#pragma unroll
    for (int k = 0; k < 4; ++k) {
      bf16x8 Bh[4], Bl[4];
#pragma unroll
      for (int n = 0; n < 4; ++n) {
        int off = (16 * n + lane) * ACT_ST + 32 * k + 8 * quad;
        Bh[n] = *(const bf16x8*)&actH[cur][off];
        Bl[n] = *(const bf16x8*)&actL[cur][off];
      }
#pragma unroll
      for (int m = 0; m < 2; ++m)
#pragma unroll
        for (int n = 0; n < 4; ++n) {
          acc[m][n] = __builtin_amdgcn_mfma_f32_16x16x32_bf16(Ah[m][k], Bh[n], acc[m][n], 0, 0, 0);
          acc[m][n] = __builtin_amdgcn_mfma_f32_16x16x32_bf16(Ah[m][k], Bl[n], acc[m][n], 0, 0, 0);
          acc[m][n] = __builtin_amdgcn_mfma_f32_16x16x32_bf16(Al[m][k], Bh[n], acc[m][n], 0, 0, 0);
        }
    }

    if (layer == 2) {
      // store: lane holds atom = 16n+lane (col), f rows = 32wv+16m+4quad+r
#pragma unroll
      for (int m = 0; m < 2; ++m) {
#pragma unroll
        for (int n = 0; n < 4; ++n) {
          int atom = base + 16 * n + lane;
          if (atom < N) {
            int f0 = 32 * wv_ + 16 * m + 4 * quad;
            *(f32x4*)(out + (size_t)atom * 128 + f0) = acc[m][n];
          }
        }
      }
    } else {
      int nxt = cur ^ 1;
#pragma unroll
      for (int m = 0; m < 2; ++m) {
#pragma unroll
        for (int n = 0; n < 4; ++n) {
          int atom = 16 * n + lane;
          int g0 = 32 * wv_ + 16 * m + 4 * quad;   // next-layer k index
          float s[4];
          if (layer == 0) {
#pragma unroll
            for (int r = 0; r < 4; ++r) s[r] = ssp_f(acc[m][n][r]);
          } else {
            float c0 = sC0[atom], c1 = sC1[atom];
#pragma unroll
            for (int r = 0; r < 4; ++r)
              s[r] = ssp_f(c0 * sWv0[g0 + r] + c1 * sWv1[g0 + r] + acc[m][n][r]);
          }
          split_store4(&actH[nxt][atom * ACT_ST + g0], &actL[nxt][atom * ACT_ST + g0], s);
        }
      }
    }
    cur ^= 1;
    __syncthreads();
  }
}

// ---------------------------------------------------------------------------
extern "C" void kernel_launch(void* const* d_in, const int* in_sizes, int n_in,
                              void* d_out, int out_size, void* d_ws, size_t ws_size,
                              hipStream_t stream) {
  const float* emb = (const float*)d_in[0];
  const float* ef  = (const float*)d_in[1];
  const int*   idx = (const int*)d_in[2];
  const float* Wq  = (const float*)d_in[3];
  const float* bq  = (const float*)d_in[4];
  const float* Wk  = (const float*)d_in[5];
  const float* Wv  = (const float*)d_in[6];
  const float* W1  = (const float*)d_in[7];
  const float* W2  = (const float*)d_in[8];
  const float* Wo  = (const float*)d_in[9];
  float* out = (float*)d_out;

  int N = in_sizes[0] / 128;
  int B = in_sizes[1];

  float* ws = (float*)d_ws;
  float* A      = ws;                      // 256
  float* bv     = ws + 256;                // 2
  unsigned* Mu  = (unsigned*)(ws + 258);   // 1
  float* Z      = ws + 259;                // 1
  float* molsum = ws + 260;                // B
  float* wvec   = ws + 260 + B;            // N
  size_t offW   = ((size_t)260 + B + N + 7) & ~(size_t)7;   // 32B-align
  short* WH     = (short*)(ws + offW);     // 3*16384 shorts
  short* WL     = WH + 3 * 16384;          // 3*16384 shorts

  k_prep<<<(B + 255) / 256, 256, 0, stream>>>(Wq, bq, Wk, A, bv, Mu, Z, molsum, B);
  k_split<<<192, 256, 0, stream>>>(W1, W2, Wo, WH, WL);
  k_w<<<(N + 15) / 16, 256, 0, stream>>>(emb, ef, idx, A, bv, wvec, Mu, N);
  k_expsum<<<(N + 255) / 256, 256, 0, stream>>>(wvec, idx, Mu, molsum, Z, N);
  k_mlp<<<(N + 63) / 64, 256, 0, stream>>>(wvec, idx, ef, Wv, WH, WL, molsum, Mu, Z, out, N);
}